// Round 2
// baseline (862.781 us; speedup 1.0000x reference)
//
#include <hip/hip_runtime.h>
#include <hip/hip_bf16.h>

#define N_NODES 100000
#define N_EDGES 3200000
#define IN_DIM  512
#define HIDDEN  16
#define NCLS    7
#define NB_N    391   // ceil(100000/256)

// ---------------- degree (self-loop = 1) ----------------
__global__ void k_init_deg(unsigned int* __restrict__ deg) {
    int i = blockIdx.x * 256 + threadIdx.x;
    if (i < N_NODES) deg[i] = 1u;
}

__global__ void k_count_deg(const int* __restrict__ dst, unsigned int* __restrict__ deg) {
    int e = blockIdx.x * 256 + threadIdx.x;
    if (e < N_EDGES) atomicAdd(&deg[dst[e]], 1u);
}

// ---------------- exclusive scan of (deg-1) -> CSR offsets ----------------
__global__ __launch_bounds__(256) void k_scan1(const unsigned int* __restrict__ deg,
                                               unsigned int* __restrict__ offs,
                                               unsigned int* __restrict__ bsum) {
    __shared__ unsigned int tmp[256];
    int n = blockIdx.x * 256 + threadIdx.x;
    unsigned int c = (n < N_NODES) ? deg[n] - 1u : 0u;
    tmp[threadIdx.x] = c;
    __syncthreads();
    for (int off = 1; off < 256; off <<= 1) {
        unsigned int v = (threadIdx.x >= off) ? tmp[threadIdx.x - off] : 0u;
        __syncthreads();
        tmp[threadIdx.x] += v;
        __syncthreads();
    }
    unsigned int inc = tmp[threadIdx.x];
    if (n < N_NODES) offs[n] = inc - c;           // exclusive within block
    if (threadIdx.x == 255) bsum[blockIdx.x] = inc;
}

__global__ __launch_bounds__(512) void k_scan2(unsigned int* __restrict__ bsum) {
    __shared__ unsigned int tmp[512];
    int i = threadIdx.x;
    unsigned int c = (i < NB_N) ? bsum[i] : 0u;
    tmp[i] = c;
    __syncthreads();
    for (int off = 1; off < 512; off <<= 1) {
        unsigned int v = (i >= off) ? tmp[i - off] : 0u;
        __syncthreads();
        tmp[i] += v;
        __syncthreads();
    }
    if (i < NB_N) bsum[i] = tmp[i] - c;           // exclusive across blocks
}

__global__ __launch_bounds__(256) void k_scan3(unsigned int* __restrict__ offs,
                                               const unsigned int* __restrict__ bsum,
                                               unsigned int* __restrict__ cursor) {
    int n = blockIdx.x * 256 + threadIdx.x;
    if (n < N_NODES) {
        unsigned int v = offs[n] + bsum[blockIdx.x];
        offs[n] = v;
        cursor[n] = v;
    }
}

// ---------------- scatter edges into CSR (int atomics only) ----------------
__global__ __launch_bounds__(256) void k_scatter(const int* __restrict__ src,
                                                 const int* __restrict__ dst,
                                                 unsigned int* __restrict__ cursor,
                                                 int* __restrict__ csr) {
    int e = blockIdx.x * 256 + threadIdx.x;
    if (e < N_EDGES) {
        unsigned int p = atomicAdd(&cursor[dst[e]], 1u);
        csr[p] = src[e];
    }
}

// ---------------- layer-1 GEMM: h1 = x @ W1, plus dinv ----------------
__global__ __launch_bounds__(256) void k_gemm1(
    const float* __restrict__ x, const float* __restrict__ W1,
    const unsigned int* __restrict__ deg,
    float* __restrict__ dinv, float* __restrict__ h1) {
    __shared__ float Xs[256 * 33];
    const int tid = threadIdx.x;
    const int n0  = blockIdx.x * 256;
    const int n   = n0 + tid;

    float acc[16];
#pragma unroll
    for (int j = 0; j < 16; ++j) acc[j] = 0.f;

    for (int kc = 0; kc < IN_DIM; kc += 32) {
        __syncthreads();
#pragma unroll
        for (int r = 0; r < 8; ++r) {
            int flat = r * 256 + tid;
            int row  = flat >> 3;
            int col  = (flat & 7) << 2;
            int gn   = n0 + row;
            if (gn < N_NODES) {
                const float4 v = *(const float4*)(x + (size_t)gn * IN_DIM + kc + col);
                float* d = &Xs[row * 33 + col];
                d[0] = v.x; d[1] = v.y; d[2] = v.z; d[3] = v.w;
            }
        }
        __syncthreads();
        if (n < N_NODES) {
#pragma unroll
            for (int i = 0; i < 32; ++i) {
                float xv = Xs[tid * 33 + i];
                const float* wr = W1 + (size_t)(kc + i) * 16;   // wave-uniform -> s_load
#pragma unroll
                for (int j = 0; j < 16; ++j) acc[j] = fmaf(xv, wr[j], acc[j]);
            }
        }
    }

    if (n < N_NODES) {
        dinv[n] = rsqrtf((float)deg[n]);
#pragma unroll
        for (int j = 0; j < 16; j += 4)
            *(float4*)(h1 + (size_t)n * 16 + j) =
                make_float4(acc[j], acc[j+1], acc[j+2], acc[j+3]);
    }
}

// ---------------- gather layer 1 + relu/bias + W2 -> h2 (stride 8) ----------------
// 256 threads = 16 nodes x 16 lanes
__global__ __launch_bounds__(256) void k_g1(
    const unsigned int* __restrict__ offs, const unsigned int* __restrict__ deg,
    const int* __restrict__ csr, const float* __restrict__ dinv,
    const float* __restrict__ h1, const float* __restrict__ b1,
    const float* __restrict__ W2, float* __restrict__ h2) {
    const int t = threadIdx.x;
    const int g = t >> 4;
    const int j = t & 15;
    const int n = blockIdx.x * 16 + g;
    __shared__ float Z[16][17];

    if (n < N_NODES) {
        const float din = dinv[n];
        const unsigned int beg = offs[n];
        const unsigned int cnt = deg[n] - 1u;
        float acc = h1[(size_t)n * 16 + j] * din * din;   // self-loop
        unsigned int k = 0;
        for (; k + 4 <= cnt; k += 4) {                    // 4 independent load chains
            int s0 = csr[beg+k+0], s1 = csr[beg+k+1], s2 = csr[beg+k+2], s3 = csr[beg+k+3];
            float w0 = dinv[s0], w1 = dinv[s1], w2 = dinv[s2], w3 = dinv[s3];
            float v0 = h1[(size_t)s0*16+j], v1 = h1[(size_t)s1*16+j],
                  v2 = h1[(size_t)s2*16+j], v3 = h1[(size_t)s3*16+j];
            acc = fmaf(v0, w0 * din, acc);
            acc = fmaf(v1, w1 * din, acc);
            acc = fmaf(v2, w2 * din, acc);
            acc = fmaf(v3, w3 * din, acc);
        }
        for (; k < cnt; ++k) {
            int s = csr[beg + k];
            acc = fmaf(h1[(size_t)s*16+j], dinv[s] * din, acc);
        }
        Z[g][j] = fmaxf(acc + b1[j], 0.f);                // relu(agg1 + b1)
    }
    __syncthreads();
    if (n < N_NODES && j < 8) {                           // z @ W2, padded to 8
        float o = 0.f;
        if (j < 7) {
#pragma unroll
            for (int k = 0; k < 16; ++k) o = fmaf(Z[g][k], W2[k * 7 + j], o);
        }
        h2[(size_t)n * 8 + j] = o;
    }
}

// ---------------- gather layer 2 + bias + log_softmax -> out ----------------
// 256 threads = 32 nodes x 8 lanes
__global__ __launch_bounds__(256) void k_g2(
    const unsigned int* __restrict__ offs, const unsigned int* __restrict__ deg,
    const int* __restrict__ csr, const float* __restrict__ dinv,
    const float* __restrict__ h2, const float* __restrict__ b2,
    float* __restrict__ out) {
    const int t = threadIdx.x;
    const int g = t >> 3;
    const int j = t & 7;
    const int n = blockIdx.x * 32 + g;
    if (n >= N_NODES) return;

    const float din = dinv[n];
    const unsigned int beg = offs[n];
    const unsigned int cnt = deg[n] - 1u;
    float acc = h2[(size_t)n * 8 + j] * din * din;        // self-loop (lane 7 reads 0)
    unsigned int k = 0;
    for (; k + 4 <= cnt; k += 4) {
        int s0 = csr[beg+k+0], s1 = csr[beg+k+1], s2 = csr[beg+k+2], s3 = csr[beg+k+3];
        float w0 = dinv[s0], w1 = dinv[s1], w2 = dinv[s2], w3 = dinv[s3];
        float v0 = h2[(size_t)s0*8+j], v1 = h2[(size_t)s1*8+j],
              v2 = h2[(size_t)s2*8+j], v3 = h2[(size_t)s3*8+j];
        acc = fmaf(v0, w0 * din, acc);
        acc = fmaf(v1, w1 * din, acc);
        acc = fmaf(v2, w2 * din, acc);
        acc = fmaf(v3, w3 * din, acc);
    }
    for (; k < cnt; ++k) {
        int s = csr[beg + k];
        acc = fmaf(h2[(size_t)s*8+j], dinv[s] * din, acc);
    }

    float v = (j < 7) ? (acc + b2[j]) : -1e30f;
    float m = v;                                           // max over 8 lanes
#pragma unroll
    for (int d = 1; d < 8; d <<= 1) m = fmaxf(m, __shfl_xor(m, d, 8));
    float e = (j < 7) ? expf(v - m) : 0.f;
    float s = e;                                           // sum over 8 lanes
#pragma unroll
    for (int d = 1; d < 8; d <<= 1) s += __shfl_xor(s, d, 8);
    if (j < 7) out[(size_t)n * 7 + j] = v - (logf(s) + m);
}

extern "C" void kernel_launch(void* const* d_in, const int* in_sizes, int n_in,
                              void* d_out, int out_size, void* d_ws, size_t ws_size,
                              hipStream_t stream) {
    const float* x  = (const float*)d_in[0];
    const int*   ei = (const int*)d_in[1];
    const float* W1 = (const float*)d_in[2];
    const float* b1 = (const float*)d_in[3];
    const float* W2 = (const float*)d_in[4];
    const float* b2 = (const float*)d_in[5];
    float* out = (float*)d_out;

    const int* src = ei;
    const int* dst = ei + N_EDGES;

    char* ws = (char*)d_ws;
    size_t o = 0;
    auto alloc = [&](size_t bytes) -> void* {
        void* p = ws + o;
        o = (o + bytes + 255) & ~(size_t)255;
        return p;
    };
    unsigned int* deg    = (unsigned int*)alloc((size_t)N_NODES * 4);
    unsigned int* offs   = (unsigned int*)alloc((size_t)N_NODES * 4);
    unsigned int* cursor = (unsigned int*)alloc((size_t)N_NODES * 4);
    unsigned int* bsum   = (unsigned int*)alloc(2048);
    float*        dinv   = (float*)alloc((size_t)N_NODES * 4);
    float*        h1     = (float*)alloc((size_t)N_NODES * 16 * 4);
    float*        h2     = (float*)alloc((size_t)N_NODES * 8 * 4);
    int*          csr    = (int*)alloc((size_t)N_EDGES * 4);

    const int nb_e = (N_EDGES + 255) / 256;
    k_init_deg <<<NB_N, 256, 0, stream>>>(deg);
    k_count_deg<<<nb_e, 256, 0, stream>>>(dst, deg);
    k_scan1    <<<NB_N, 256, 0, stream>>>(deg, offs, bsum);
    k_scan2    <<<1, 512, 0, stream>>>(bsum);
    k_scan3    <<<NB_N, 256, 0, stream>>>(offs, bsum, cursor);
    k_scatter  <<<nb_e, 256, 0, stream>>>(src, dst, cursor, csr);
    k_gemm1    <<<NB_N, 256, 0, stream>>>(x, W1, deg, dinv, h1);
    k_g1       <<<(N_NODES + 15) / 16, 256, 0, stream>>>(offs, deg, csr, dinv, h1, b1, W2, h2);
    k_g2       <<<(N_NODES + 31) / 32, 256, 0, stream>>>(offs, deg, csr, dinv, h2, b2, out);
}